// Round 7
// baseline (499.992 us; speedup 1.0000x reference)
//
#include <hip/hip_runtime.h>
#include <hip/hip_bf16.h>
#include <cstdint>
#include <cstddef>

// ActorHead fused pipeline, bf16 MFMA throughout.
//   K1 k_qkv : LDS-tiled GEMM-BT [4096x1536x512], 128x64 tiles (768 wgs, 3 wg/CU)
//              -> Qb row-major (scaled), Kp/Vp MFMA-fragment-packed (verified r6 mapping)
//   K2 k_attn: split-K(S=8) flash attention, S^T ordering, P register-resident,
//              distance-2 prefetch of mask/weight (the only HBM-latency loads).
//              No LDS, no barriers. masked -> e=0 -> p=0 exactly.
//   K2b k_comb: merge splits, influence, valid
//   K3 k_fold: fold out_w over heads; K4 k_out: [4096x128x512] GEMM (256 wgs)
// d_out = topic[4096*128] fp32 ++ influence[4096] fp32

typedef __attribute__((ext_vector_type(8))) short bf16x8;
typedef __attribute__((ext_vector_type(4))) short bf16x4;
typedef __attribute__((ext_vector_type(4))) float f32x4;

#define MFMA32(a, b, c) __builtin_amdgcn_mfma_f32_16x16x32_bf16((a), (b), (c), 0, 0, 0)
// K=16 bf16 MFMA: gfx90a-era "_1k" spelling; maps to v_mfma_f32_16x16x16_bf16 (valid gfx950).
#define MFMA16(a, b, c) __builtin_amdgcn_mfma_f32_16x16x16bf16_1k((a), (b), (c), 0, 0, 0)

static __device__ __forceinline__ short f2b(float x) {
  union { float f; unsigned u; } v; v.f = x;
  unsigned r = v.u + 0x7fffu + ((v.u >> 16) & 1u);  // RNE to bf16
  return (short)(r >> 16);
}

// ---------------- K1: QKV projection (LDS-tiled 128x64, packed epilogue) ----------------
__global__ __launch_bounds__(256) void k_qkv(
    const float* __restrict__ a, const float* __restrict__ kv,
    const float* __restrict__ w, const float* __restrict__ bias,
    short* __restrict__ Qb, short* __restrict__ Kp, short* __restrict__ Vp)
{
  __shared__ short As[128 * 40];
  __shared__ short Bs[64 * 40];
  const int blk = blockIdx.x;
  const int bm = blk % 32, bn = blk / 32;  // bn 0..23; consecutive blocks share w-slice
  const int m0 = bm * 128, n0 = bn * 64;
  const float* __restrict__ Ain = (bn < 8) ? a : kv;
  const int tid = threadIdx.x;
  const int lane = tid & 63, wvi = tid >> 6;
  const int wm = (wvi >> 1) * 64, wn = (wvi & 1) * 32;
  const int c = lane & 15, g = lane >> 4;
  const int srA = tid >> 1, scA = (tid & 1) * 16;
  const int srB = tid >> 2, scB = (tid & 3) * 8;

  f32x4 acc[4][2];
#pragma unroll
  for (int i = 0; i < 4; ++i)
#pragma unroll
    for (int j = 0; j < 2; ++j) acc[i][j] = (f32x4)0.f;

  for (int k0 = 0; k0 < 512; k0 += 32) {
    const float* ap = Ain + (size_t)(m0 + srA) * 512 + k0 + scA;
#pragma unroll
    for (int j = 0; j < 4; ++j) {
      f32x4 av = *(const f32x4*)(ap + 4 * j);
      bf16x4 as;
      as.x = f2b(av.x); as.y = f2b(av.y); as.z = f2b(av.z); as.w = f2b(av.w);
      *(bf16x4*)(&As[srA * 40 + scA + 4 * j]) = as;
    }
    const float* bp = w + (size_t)(n0 + srB) * 512 + k0 + scB;
#pragma unroll
    for (int j = 0; j < 2; ++j) {
      f32x4 bv = *(const f32x4*)(bp + 4 * j);
      bf16x4 bs;
      bs.x = f2b(bv.x); bs.y = f2b(bv.y); bs.z = f2b(bv.z); bs.w = f2b(bv.w);
      *(bf16x4*)(&Bs[srB * 40 + scB + 4 * j]) = bs;
    }
    __syncthreads();
    bf16x8 af[4], bfg[2];
#pragma unroll
    for (int t = 0; t < 4; ++t)
      af[t] = *(const bf16x8*)(&As[(wm + t * 16 + c) * 40 + g * 8]);
#pragma unroll
    for (int t = 0; t < 2; ++t)
      bfg[t] = *(const bf16x8*)(&Bs[(wn + t * 16 + c) * 40 + g * 8]);
#pragma unroll
    for (int rt = 0; rt < 4; ++rt)
#pragma unroll
      for (int ct = 0; ct < 2; ++ct)
        acc[rt][ct] = MFMA32(af[rt], bfg[ct], acc[rt][ct]);
    __syncthreads();
  }

#pragma unroll
  for (int ct = 0; ct < 2; ++ct) {
    const int col = n0 + wn + ct * 16 + c;
    const float bj = bias[col];
#pragma unroll
    for (int rt = 0; rt < 4; ++rt) {
      const int row = m0 + wm + rt * 16 + g * 4;  // row&15 = g*4
      const int mc = row >> 4;
      if (col < 512) {
#pragma unroll
        for (int r = 0; r < 4; ++r)
          Qb[(size_t)(row + r) * 512 + col] = f2b((acc[rt][ct][r] + bj) * 0.08838834764831843f);
      } else if (col < 1024) {
        const int colK = col - 512;
        const int h = colK >> 7, dk = colK & 127;
        const int ks = dk >> 5, gk = (dk >> 3) & 3, j = dk & 7;
        short* base = Kp + (size_t)((((h * 256 + mc) * 4 + ks) * 64) + gk * 16 + g * 4) * 8 + j;
#pragma unroll
        for (int r = 0; r < 4; ++r) base[r * 8] = f2b(acc[rt][ct][r] + bj);
      } else {
        const int colV = col - 1024;
        const int h = colV >> 7, db = (colV & 127) >> 4, cv = colV & 15;
        bf16x4 pk;
#pragma unroll
        for (int r = 0; r < 4; ++r) pk[r] = f2b(acc[rt][ct][r] + bj);
        *(bf16x4*)(Vp + (size_t)((((h * 256 + mc) * 8 + db) * 64) + g * 16 + cv) * 4) = pk;
      }
    }
  }
}

// ---------------- K2: split-K flash attention (packed frags + dist-2 mask/wgt prefetch) ----
__global__ __launch_bounds__(256, 4) void k_attn(
    const short* __restrict__ Qb, const short* __restrict__ Kp,
    const short* __restrict__ Vp, const float* __restrict__ wgt,
    const int* __restrict__ msk, const int S,
    short* __restrict__ Opart, float* __restrict__ lpart,
    float* __restrict__ cipart, float* __restrict__ lbpart)
{
  const int bx = blockIdx.x;
  const int rb = bx & 255, sp = bx >> 8;
  const int n0 = rb * 16;
  const int mlen = 4096 / S;          // S in {8,4,2,1} -> nch even
  const int mc0 = (sp * mlen) >> 4;
  const int nch = mlen >> 4;
  const int tid = threadIdx.x;
  const int lane = tid & 63, h = tid >> 6;
  const int c = lane & 15, g = lane >> 4;

  bf16x8 qf[4];
#pragma unroll
  for (int ks = 0; ks < 4; ++ks)
    qf[ks] = *(const bf16x8*)(Qb + (size_t)(n0 + c) * 512 + h * 128 + ks * 32 + g * 8);

  f32x4 O[8];
#pragma unroll
  for (int db = 0; db < 8; ++db) O[db] = (f32x4)0.f;
  float lh = 0.f, lb = 0.f, ci = 0.f;

  const short* Kw = Kp + (size_t)h * 524288 + (size_t)lane * 8 + (size_t)mc0 * 2048;
  const short* Vw = Vp + (size_t)h * 524288 + (size_t)lane * 4 + (size_t)mc0 * 2048;
  const int* mbase_p = msk + (size_t)(n0 + c) * 4096 + g * 4 + (size_t)mc0 * 16;
  const float* wbase_p = wgt + (size_t)(n0 + c) * 4096 + g * 4 + (size_t)mc0 * 16;

  auto chunk = [&](int t, const int4& mk, const f32x4& wv) {
    bf16x8 kf[4];
#pragma unroll
    for (int ks = 0; ks < 4; ++ks)
      kf[ks] = *(const bf16x8*)(Kw + t * 2048 + ks * 512);
    f32x4 Sv = (f32x4)0.f;
#pragma unroll
    for (int ks = 0; ks < 4; ++ks) Sv = MFMA32(kf[ks], qf[ks], Sv);
    const float e0 = mk.x ? __expf(wv.x) : 0.f;
    const float e1 = mk.y ? __expf(wv.y) : 0.f;
    const float e2 = mk.z ? __expf(wv.z) : 0.f;
    const float e3 = mk.w ? __expf(wv.w) : 0.f;
    const float p0 = __expf(Sv[0]) * e0, p1 = __expf(Sv[1]) * e1;
    const float p2 = __expf(Sv[2]) * e2, p3 = __expf(Sv[3]) * e3;
    lh += (p0 + p1) + (p2 + p3);
    lb += (e0 + e1) + (e2 + e3);
    ci += (p0 * e0 + p1 * e1) + (p2 * e2 + p3 * e3);
    bf16x4 pa;
    pa[0] = f2b(p0); pa[1] = f2b(p1); pa[2] = f2b(p2); pa[3] = f2b(p3);
#pragma unroll
    for (int db = 0; db < 8; ++db) {
      const bf16x4 vf = *(const bf16x4*)(Vw + t * 2048 + db * 256);
      O[db] = MFMA16(pa, vf, O[db]);
    }
  };

  // distance-2 software pipeline on the HBM-latency loads (mask/weight)
  int4 mkA = *(const int4*)(mbase_p);
  f32x4 wvA = *(const f32x4*)(wbase_p);
  int4 mkB = *(const int4*)(mbase_p + 16);
  f32x4 wvB = *(const f32x4*)(wbase_p + 16);

  for (int t = 0; t < nch; t += 2) {
    int4 mkC = mkA, mkD = mkB;
    f32x4 wvC = wvA, wvD = wvB;
    if (t + 2 < nch) { mkC = *(const int4*)(mbase_p + (t + 2) * 16); wvC = *(const f32x4*)(wbase_p + (t + 2) * 16); }
    if (t + 3 < nch) { mkD = *(const int4*)(mbase_p + (t + 3) * 16); wvD = *(const f32x4*)(wbase_p + (t + 3) * 16); }
    chunk(t, mkA, wvA);
    chunk(t + 1, mkB, wvB);
    mkA = mkC; wvA = wvC; mkB = mkD; wvB = wvD;
  }

  // reduce over g-groups (lanes ^16, ^32 share actor n=c)
  lh += __shfl_xor(lh, 16, 64); lh += __shfl_xor(lh, 32, 64);
  lb += __shfl_xor(lb, 16, 64); lb += __shfl_xor(lb, 32, 64);
  ci += __shfl_xor(ci, 16, 64); ci += __shfl_xor(ci, 32, 64);

  float inv[4];
#pragma unroll
  for (int r = 0; r < 4; ++r)
    inv[r] = 1.f / fmaxf(__shfl(lh, 4 * g + r, 64), 1e-30f);
#pragma unroll
  for (int db = 0; db < 8; ++db)
#pragma unroll
    for (int r = 0; r < 4; ++r)
      Opart[(size_t)sp * (4096 * 512) + (size_t)(n0 + g * 4 + r) * 512 +
            h * 128 + db * 16 + c] = f2b(O[db][r] * inv[r]);

  if (g == 0) {
    const int row = n0 + c;
    lpart[((size_t)sp * 4 + h) * 4096 + row] = lh;
    cipart[((size_t)sp * 4 + h) * 4096 + row] = ci;
    if (h == 0) lbpart[(size_t)sp * 4096 + row] = lb;
  }
}

// ---------------- K2b: combine splits ----------------
__global__ __launch_bounds__(256) void k_comb(
    const short* __restrict__ Opart, const float* __restrict__ lpart,
    const float* __restrict__ cipart, const float* __restrict__ lbpart,
    const int S, short* __restrict__ ctxb, float* __restrict__ validw,
    float* __restrict__ infl)
{
  const int tid = threadIdx.x;
  const int rloc = tid >> 5, cseg = tid & 31;
  const int row = blockIdx.x * 8 + rloc;
  const int col0 = cseg * 16;
  const int h = col0 >> 7;

  float l[4], ciS[4], lb = 0.f;
#pragma unroll
  for (int hh = 0; hh < 4; ++hh) { l[hh] = 0.f; ciS[hh] = 0.f; }
  for (int s = 0; s < S; ++s) {
#pragma unroll
    for (int hh = 0; hh < 4; ++hh) {
      l[hh]   += lpart[((size_t)s * 4 + hh) * 4096 + row];
      ciS[hh] += cipart[((size_t)s * 4 + hh) * 4096 + row];
    }
    lb += lbpart[(size_t)s * 4096 + row];
  }

  float acc[16];
#pragma unroll
  for (int j = 0; j < 16; ++j) acc[j] = 0.f;
  const float linv = 1.f / fmaxf(l[h], 1e-30f);
  for (int s = 0; s < S; ++s) {
    const float w_s = lpart[((size_t)s * 4 + h) * 4096 + row] * linv;
    const bf16x8 o0 = *(const bf16x8*)(Opart + (size_t)s * (4096 * 512) + (size_t)row * 512 + col0);
    const bf16x8 o1 = *(const bf16x8*)(Opart + (size_t)s * (4096 * 512) + (size_t)row * 512 + col0 + 8);
#pragma unroll
    for (int j = 0; j < 8; ++j) {
      union { unsigned u; float f; } v0, v1;
      v0.u = ((unsigned)(unsigned short)o0[j]) << 16;
      v1.u = ((unsigned)(unsigned short)o1[j]) << 16;
      acc[j]     += w_s * v0.f;
      acc[8 + j] += w_s * v1.f;
    }
  }
  bf16x8 c0, c1;
#pragma unroll
  for (int j = 0; j < 8; ++j) { c0[j] = f2b(acc[j]); c1[j] = f2b(acc[8 + j]); }
  *(bf16x8*)(ctxb + (size_t)row * 512 + col0) = c0;
  *(bf16x8*)(ctxb + (size_t)row * 512 + col0 + 8) = c1;

  if (cseg == 0) {
    validw[row] = (lb > 0.f) ? 1.f : 0.f;
    float s_ = 0.f;
#pragma unroll
    for (int hh = 0; hh < 4; ++hh) s_ += ciS[hh] / fmaxf(l[hh], 1e-30f);
    infl[row] = (lb > 0.f) ? s_ / (4.f * lb) : 0.f;
  }
}

// ---------------- K3: fold out_w over heads ----------------
__global__ void k_fold(const float* __restrict__ ow, const float* __restrict__ ob,
                       short* __restrict__ Wf, float* __restrict__ bfo)
{
  const int idx = blockIdx.x * 256 + threadIdx.x;
  if (idx < 128 * 512) {
    const int dk = idx >> 9, d = idx & 511;
    const float s = 0.25f * (ow[(size_t)dk * 512 + d] + ow[(size_t)(dk + 128) * 512 + d] +
                             ow[(size_t)(dk + 256) * 512 + d] + ow[(size_t)(dk + 384) * 512 + d]);
    Wf[(size_t)dk * 512 + d] = f2b(s);
  }
  if (idx < 128) bfo[idx] = 0.25f * (ob[idx] + ob[idx + 128] + ob[idx + 256] + ob[idx + 384]);
}

// ---------------- K4: topic = ctx @ Wfold^T + bfold (256 wgs, direct frags) ----------------
__global__ __launch_bounds__(256) void k_out(
    const short* __restrict__ ctxb, const short* __restrict__ Wf,
    const float* __restrict__ bfo, const float* __restrict__ validw,
    float* __restrict__ topic)
{
  const int tid = threadIdx.x;
  const int lane = tid & 63, wvi = tid >> 6;
  const int m0 = blockIdx.x * 16;
  const int c = lane & 15, g = lane >> 4;

  f32x4 acc[2];
  acc[0] = (f32x4)0.f; acc[1] = (f32x4)0.f;

  for (int k0 = 0; k0 < 512; k0 += 32) {
    const bf16x8 af = *(const bf16x8*)(ctxb + (size_t)(m0 + c) * 512 + k0 + g * 8);
#pragma unroll
    for (int dbl = 0; dbl < 2; ++dbl) {
      const bf16x8 bfr = *(const bf16x8*)(Wf + (size_t)(wvi * 32 + dbl * 16 + c) * 512 + k0 + g * 8);
      acc[dbl] = MFMA32(af, bfr, acc[dbl]);
    }
  }

#pragma unroll
  for (int r = 0; r < 4; ++r) {
    const int row = m0 + g * 4 + r;
    const float va = validw[row];
#pragma unroll
    for (int dbl = 0; dbl < 2; ++dbl) {
      const int col = wvi * 32 + dbl * 16 + c;
      const float vl = (va > 0.5f) ? (acc[dbl][r] + bfo[col]) : 0.f;
      topic[(size_t)row * 128 + col] = vl;
    }
  }
}

extern "C" void kernel_launch(void* const* d_in, const int* in_sizes, int n_in,
                              void* d_out, int out_size, void* d_ws, size_t ws_size,
                              hipStream_t stream) {
  const float* a_z  = (const float*)d_in[0];
  const float* bv_z = (const float*)d_in[1];
  const int*   mask = (const int*)d_in[2];
  const float* wgt  = (const float*)d_in[3];
  const float* ipw  = (const float*)d_in[4];
  const float* ipb  = (const float*)d_in[5];
  const float* ow   = (const float*)d_in[6];
  const float* ob   = (const float*)d_in[7];
  float* topic = (float*)d_out;              // [4096 x 128]
  float* infl  = (float*)d_out + 4096 * 128; // [4096]

  const size_t MB = (size_t)1 << 20;
  char* ws = (char*)d_ws;
  short* Qb     = (short*)(ws);                    // 4 MB
  short* Kp     = (short*)(ws + 4 * MB);           // 4 MB packed K frags
  short* Vp     = (short*)(ws + 8 * MB);           // 4 MB packed V frags
  short* ctxb   = (short*)(ws + 12 * MB);          // 4 MB
  float* validw = (float*)(ws + 16 * MB);          // 16 KB
  short* Wf     = (short*)(ws + 16 * MB + (64 << 10));   // 128 KB
  float* bfo    = (float*)(ws + 16 * MB + (224 << 10));  // 512 B
  const size_t pbase0 = 16 * MB + (256 << 10);

  // per split: Opart 4MB + lpart 64KB + cipart 64KB + lbpart 16KB
  auto need = [&](int S) { return pbase0 + (size_t)S * (4 * MB + (144 << 10)); };
  int S = 8;
  while (S > 1 && need(S) > ws_size) S >>= 1;

  char* pbase = ws + pbase0;
  short* Opart  = (short*)(pbase);
  float* lpart  = (float*)(pbase + (size_t)S * 4 * MB);
  float* cipart = (float*)(pbase + (size_t)S * 4 * MB + ((size_t)S << 16));
  float* lbpart = (float*)(pbase + (size_t)S * 4 * MB + ((size_t)S << 17));

  k_qkv <<<768, 256, 0, stream>>>(a_z, bv_z, ipw, ipb, Qb, Kp, Vp);
  k_fold<<<256, 256, 0, stream>>>(ow, ob, Wf, bfo);
  k_attn<<<256 * S, 256, 0, stream>>>(Qb, Kp, Vp, wgt, mask, S, Opart, lpart, cipart, lbpart);
  k_comb<<<512, 256, 0, stream>>>(Opart, lpart, cipart, lbpart, S, ctxb, validw, infl);
  k_out <<<256, 256, 0, stream>>>(ctxb, Wf, bfo, validw, topic);
}

// Round 8
// 350.684 us; speedup vs baseline: 1.4258x; 1.4258x over previous
//
#include <hip/hip_runtime.h>
#include <hip/hip_bf16.h>
#include <cstdint>
#include <cstddef>

// ActorHead fused pipeline, bf16 MFMA throughout.
//   K1 k_qkv : LDS-tiled GEMM-BT [4096x1536x512], 128x64 tiles (768 wgs)
//              -> Qb row-major (scaled), Kp/Vp MFMA-fragment-packed
//   K2 k_attn: split-K(S=4) flash attention, S^T ordering, P register-resident.
//              vmcnt-ordered prefetch: per chunk issue K,V first, then NEXT chunk's
//              mask/weight — waiting on K/V (vmcnt(2)) leaves mask in flight a full
//              iteration. Minimal prefetch state (8 VGPRs) -> no scratch spill.
//   K2b k_comb: merge splits, influence, valid
//   K3 k_fold: fold out_w over heads; K4 k_out: [4096x128x512] GEMM (256 wgs)
// d_out = topic[4096*128] fp32 ++ influence[4096] fp32

typedef __attribute__((ext_vector_type(8))) short bf16x8;
typedef __attribute__((ext_vector_type(4))) short bf16x4;
typedef __attribute__((ext_vector_type(4))) float f32x4;

#define MFMA32(a, b, c) __builtin_amdgcn_mfma_f32_16x16x32_bf16((a), (b), (c), 0, 0, 0)
// K=16 bf16 MFMA: gfx90a-era "_1k" spelling; maps to v_mfma_f32_16x16x16_bf16 (valid gfx950).
#define MFMA16(a, b, c) __builtin_amdgcn_mfma_f32_16x16x16bf16_1k((a), (b), (c), 0, 0, 0)

static __device__ __forceinline__ short f2b(float x) {
  union { float f; unsigned u; } v; v.f = x;
  unsigned r = v.u + 0x7fffu + ((v.u >> 16) & 1u);  // RNE to bf16
  return (short)(r >> 16);
}

// ---------------- K1: QKV projection (LDS-tiled 128x64, packed epilogue) ----------------
__global__ __launch_bounds__(256) void k_qkv(
    const float* __restrict__ a, const float* __restrict__ kv,
    const float* __restrict__ w, const float* __restrict__ bias,
    short* __restrict__ Qb, short* __restrict__ Kp, short* __restrict__ Vp)
{
  __shared__ short As[128 * 40];
  __shared__ short Bs[64 * 40];
  const int blk = blockIdx.x;
  const int bm = blk % 32, bn = blk / 32;  // bn 0..23; consecutive blocks share w-slice
  const int m0 = bm * 128, n0 = bn * 64;
  const float* __restrict__ Ain = (bn < 8) ? a : kv;
  const int tid = threadIdx.x;
  const int lane = tid & 63, wvi = tid >> 6;
  const int wm = (wvi >> 1) * 64, wn = (wvi & 1) * 32;
  const int c = lane & 15, g = lane >> 4;
  const int srA = tid >> 1, scA = (tid & 1) * 16;
  const int srB = tid >> 2, scB = (tid & 3) * 8;

  f32x4 acc[4][2];
#pragma unroll
  for (int i = 0; i < 4; ++i)
#pragma unroll
    for (int j = 0; j < 2; ++j) acc[i][j] = (f32x4)0.f;

  for (int k0 = 0; k0 < 512; k0 += 32) {
    const float* ap = Ain + (size_t)(m0 + srA) * 512 + k0 + scA;
#pragma unroll
    for (int j = 0; j < 4; ++j) {
      f32x4 av = *(const f32x4*)(ap + 4 * j);
      bf16x4 as;
      as.x = f2b(av.x); as.y = f2b(av.y); as.z = f2b(av.z); as.w = f2b(av.w);
      *(bf16x4*)(&As[srA * 40 + scA + 4 * j]) = as;
    }
    const float* bp = w + (size_t)(n0 + srB) * 512 + k0 + scB;
#pragma unroll
    for (int j = 0; j < 2; ++j) {
      f32x4 bv = *(const f32x4*)(bp + 4 * j);
      bf16x4 bs;
      bs.x = f2b(bv.x); bs.y = f2b(bv.y); bs.z = f2b(bv.z); bs.w = f2b(bv.w);
      *(bf16x4*)(&Bs[srB * 40 + scB + 4 * j]) = bs;
    }
    __syncthreads();
    bf16x8 af[4], bfg[2];
#pragma unroll
    for (int t = 0; t < 4; ++t)
      af[t] = *(const bf16x8*)(&As[(wm + t * 16 + c) * 40 + g * 8]);
#pragma unroll
    for (int t = 0; t < 2; ++t)
      bfg[t] = *(const bf16x8*)(&Bs[(wn + t * 16 + c) * 40 + g * 8]);
#pragma unroll
    for (int rt = 0; rt < 4; ++rt)
#pragma unroll
      for (int ct = 0; ct < 2; ++ct)
        acc[rt][ct] = MFMA32(af[rt], bfg[ct], acc[rt][ct]);
    __syncthreads();
  }

#pragma unroll
  for (int ct = 0; ct < 2; ++ct) {
    const int col = n0 + wn + ct * 16 + c;
    const float bj = bias[col];
#pragma unroll
    for (int rt = 0; rt < 4; ++rt) {
      const int row = m0 + wm + rt * 16 + g * 4;  // row&15 = g*4
      const int mc = row >> 4;
      if (col < 512) {
#pragma unroll
        for (int r = 0; r < 4; ++r)
          Qb[(size_t)(row + r) * 512 + col] = f2b((acc[rt][ct][r] + bj) * 0.08838834764831843f);
      } else if (col < 1024) {
        const int colK = col - 512;
        const int h = colK >> 7, dk = colK & 127;
        const int ks = dk >> 5, gk = (dk >> 3) & 3, j = dk & 7;
        short* base = Kp + (size_t)((((h * 256 + mc) * 4 + ks) * 64) + gk * 16 + g * 4) * 8 + j;
#pragma unroll
        for (int r = 0; r < 4; ++r) base[r * 8] = f2b(acc[rt][ct][r] + bj);
      } else {
        const int colV = col - 1024;
        const int h = colV >> 7, db = (colV & 127) >> 4, cv = colV & 15;
        bf16x4 pk;
#pragma unroll
        for (int r = 0; r < 4; ++r) pk[r] = f2b(acc[rt][ct][r] + bj);
        *(bf16x4*)(Vp + (size_t)((((h * 256 + mc) * 8 + db) * 64) + g * 16 + cv) * 4) = pk;
      }
    }
  }
}

// ---------------- K2: split-K flash attention (vmcnt-ordered mask prefetch) ----------------
__global__ __launch_bounds__(256, 4) void k_attn(
    const short* __restrict__ Qb, const short* __restrict__ Kp,
    const short* __restrict__ Vp, const float* __restrict__ wgt,
    const int* __restrict__ msk, const int S,
    short* __restrict__ Opart, float* __restrict__ lpart,
    float* __restrict__ cipart, float* __restrict__ lbpart)
{
  const int bx = blockIdx.x;
  const int rb = bx & 255, sp = bx >> 8;
  const int n0 = rb * 16;
  const int mlen = 4096 / S;
  const int mc0 = (sp * mlen) >> 4;
  const int nch = mlen >> 4;
  const int tid = threadIdx.x;
  const int lane = tid & 63, h = tid >> 6;
  const int c = lane & 15, g = lane >> 4;

  bf16x8 qf[4];
#pragma unroll
  for (int ks = 0; ks < 4; ++ks)
    qf[ks] = *(const bf16x8*)(Qb + (size_t)(n0 + c) * 512 + h * 128 + ks * 32 + g * 8);

  f32x4 O[8];
#pragma unroll
  for (int db = 0; db < 8; ++db) O[db] = (f32x4)0.f;
  float lh = 0.f, lb = 0.f, ci = 0.f;

  const short* Kw = Kp + (size_t)h * 524288 + (size_t)lane * 8 + (size_t)mc0 * 2048;
  const short* Vw = Vp + (size_t)h * 524288 + (size_t)lane * 4 + (size_t)mc0 * 2048;
  const int* mbase_p = msk + (size_t)(n0 + c) * 4096 + g * 4 + (size_t)mc0 * 16;
  const float* wbase_p = wgt + (size_t)(n0 + c) * 4096 + g * 4 + (size_t)mc0 * 16;

  // prefetch chunk 0 mask/weight
  int4 mkN = *(const int4*)(mbase_p);
  f32x4 wvN = *(const f32x4*)(wbase_p);

  for (int t = 0; t < nch; ++t) {
    // 1) issue K and V loads for this chunk FIRST (older in vmcnt order)
    bf16x8 kf[4];
#pragma unroll
    for (int ks = 0; ks < 4; ++ks)
      kf[ks] = *(const bf16x8*)(Kw + t * 2048 + ks * 512);
    bf16x4 vf[8];
#pragma unroll
    for (int db = 0; db < 8; ++db)
      vf[db] = *(const bf16x4*)(Vw + t * 2048 + db * 256);

    // 2) rotate current mask, issue NEXT chunk's mask/weight (youngest -> not drained
    //    by the vmcnt wait on K/V; gets a full iteration of flight time)
    const int4 mkC = mkN;
    const f32x4 wvC = wvN;
    const int tn = (t + 1 < nch) ? (t + 1) : t;
    mkN = *(const int4*)(mbase_p + tn * 16);
    wvN = *(const f32x4*)(wbase_p + tn * 16);

    // 3) compute (waits only on K/V)
    f32x4 Sv = (f32x4)0.f;
#pragma unroll
    for (int ks = 0; ks < 4; ++ks) Sv = MFMA32(kf[ks], qf[ks], Sv);
    const float e0 = mkC.x ? __expf(wvC.x) : 0.f;
    const float e1 = mkC.y ? __expf(wvC.y) : 0.f;
    const float e2 = mkC.z ? __expf(wvC.z) : 0.f;
    const float e3 = mkC.w ? __expf(wvC.w) : 0.f;
    const float p0 = __expf(Sv[0]) * e0, p1 = __expf(Sv[1]) * e1;
    const float p2 = __expf(Sv[2]) * e2, p3 = __expf(Sv[3]) * e3;
    lh += (p0 + p1) + (p2 + p3);
    lb += (e0 + e1) + (e2 + e3);
    ci += (p0 * e0 + p1 * e1) + (p2 * e2 + p3 * e3);
    bf16x4 pa;
    pa[0] = f2b(p0); pa[1] = f2b(p1); pa[2] = f2b(p2); pa[3] = f2b(p3);
#pragma unroll
    for (int db = 0; db < 8; ++db)
      O[db] = MFMA16(pa, vf[db], O[db]);
  }

  // reduce over g-groups (lanes ^16, ^32 share actor n=c)
  lh += __shfl_xor(lh, 16, 64); lh += __shfl_xor(lh, 32, 64);
  lb += __shfl_xor(lb, 16, 64); lb += __shfl_xor(lb, 32, 64);
  ci += __shfl_xor(ci, 16, 64); ci += __shfl_xor(ci, 32, 64);

  float inv[4];
#pragma unroll
  for (int r = 0; r < 4; ++r)
    inv[r] = 1.f / fmaxf(__shfl(lh, 4 * g + r, 64), 1e-30f);
#pragma unroll
  for (int db = 0; db < 8; ++db)
#pragma unroll
    for (int r = 0; r < 4; ++r)
      Opart[(size_t)sp * (4096 * 512) + (size_t)(n0 + g * 4 + r) * 512 +
            h * 128 + db * 16 + c] = f2b(O[db][r] * inv[r]);

  if (g == 0) {
    const int row = n0 + c;
    lpart[((size_t)sp * 4 + h) * 4096 + row] = lh;
    cipart[((size_t)sp * 4 + h) * 4096 + row] = ci;
    if (h == 0) lbpart[(size_t)sp * 4096 + row] = lb;
  }
}

// ---------------- K2b: combine splits ----------------
__global__ __launch_bounds__(256) void k_comb(
    const short* __restrict__ Opart, const float* __restrict__ lpart,
    const float* __restrict__ cipart, const float* __restrict__ lbpart,
    const int S, short* __restrict__ ctxb, float* __restrict__ validw,
    float* __restrict__ infl)
{
  const int tid = threadIdx.x;
  const int rloc = tid >> 5, cseg = tid & 31;
  const int row = blockIdx.x * 8 + rloc;
  const int col0 = cseg * 16;
  const int h = col0 >> 7;

  float l[4], ciS[4], lb = 0.f;
#pragma unroll
  for (int hh = 0; hh < 4; ++hh) { l[hh] = 0.f; ciS[hh] = 0.f; }
  for (int s = 0; s < S; ++s) {
#pragma unroll
    for (int hh = 0; hh < 4; ++hh) {
      l[hh]   += lpart[((size_t)s * 4 + hh) * 4096 + row];
      ciS[hh] += cipart[((size_t)s * 4 + hh) * 4096 + row];
    }
    lb += lbpart[(size_t)s * 4096 + row];
  }

  float acc[16];
#pragma unroll
  for (int j = 0; j < 16; ++j) acc[j] = 0.f;
  const float linv = 1.f / fmaxf(l[h], 1e-30f);
  for (int s = 0; s < S; ++s) {
    const float w_s = lpart[((size_t)s * 4 + h) * 4096 + row] * linv;
    const bf16x8 o0 = *(const bf16x8*)(Opart + (size_t)s * (4096 * 512) + (size_t)row * 512 + col0);
    const bf16x8 o1 = *(const bf16x8*)(Opart + (size_t)s * (4096 * 512) + (size_t)row * 512 + col0 + 8);
#pragma unroll
    for (int j = 0; j < 8; ++j) {
      union { unsigned u; float f; } v0, v1;
      v0.u = ((unsigned)(unsigned short)o0[j]) << 16;
      v1.u = ((unsigned)(unsigned short)o1[j]) << 16;
      acc[j]     += w_s * v0.f;
      acc[8 + j] += w_s * v1.f;
    }
  }
  bf16x8 c0, c1;
#pragma unroll
  for (int j = 0; j < 8; ++j) { c0[j] = f2b(acc[j]); c1[j] = f2b(acc[8 + j]); }
  *(bf16x8*)(ctxb + (size_t)row * 512 + col0) = c0;
  *(bf16x8*)(ctxb + (size_t)row * 512 + col0 + 8) = c1;

  if (cseg == 0) {
    validw[row] = (lb > 0.f) ? 1.f : 0.f;
    float s_ = 0.f;
#pragma unroll
    for (int hh = 0; hh < 4; ++hh) s_ += ciS[hh] / fmaxf(l[hh], 1e-30f);
    infl[row] = (lb > 0.f) ? s_ / (4.f * lb) : 0.f;
  }
}

// ---------------- K3: fold out_w over heads ----------------
__global__ void k_fold(const float* __restrict__ ow, const float* __restrict__ ob,
                       short* __restrict__ Wf, float* __restrict__ bfo)
{
  const int idx = blockIdx.x * 256 + threadIdx.x;
  if (idx < 128 * 512) {
    const int dk = idx >> 9, d = idx & 511;
    const float s = 0.25f * (ow[(size_t)dk * 512 + d] + ow[(size_t)(dk + 128) * 512 + d] +
                             ow[(size_t)(dk + 256) * 512 + d] + ow[(size_t)(dk + 384) * 512 + d]);
    Wf[(size_t)dk * 512 + d] = f2b(s);
  }
  if (idx < 128) bfo[idx] = 0.25f * (ob[idx] + ob[idx + 128] + ob[idx + 256] + ob[idx + 384]);
}

// ---------------- K4: topic = ctx @ Wfold^T + bfold (256 wgs, direct frags) ----------------
__global__ __launch_bounds__(256) void k_out(
    const short* __restrict__ ctxb, const short* __restrict__ Wf,
    const float* __restrict__ bfo, const float* __restrict__ validw,
    float* __restrict__ topic)
{
  const int tid = threadIdx.x;
  const int lane = tid & 63, wvi = tid >> 6;
  const int m0 = blockIdx.x * 16;
  const int c = lane & 15, g = lane >> 4;

  f32x4 acc[2];
  acc[0] = (f32x4)0.f; acc[1] = (f32x4)0.f;

  for (int k0 = 0; k0 < 512; k0 += 32) {
    const bf16x8 af = *(const bf16x8*)(ctxb + (size_t)(m0 + c) * 512 + k0 + g * 8);
#pragma unroll
    for (int dbl = 0; dbl < 2; ++dbl) {
      const bf16x8 bfr = *(const bf16x8*)(Wf + (size_t)(wvi * 32 + dbl * 16 + c) * 512 + k0 + g * 8);
      acc[dbl] = MFMA32(af, bfr, acc[dbl]);
    }
  }

#pragma unroll
  for (int r = 0; r < 4; ++r) {
    const int row = m0 + g * 4 + r;
    const float va = validw[row];
#pragma unroll
    for (int dbl = 0; dbl < 2; ++dbl) {
      const int col = wvi * 32 + dbl * 16 + c;
      const float vl = (va > 0.5f) ? (acc[dbl][r] + bfo[col]) : 0.f;
      topic[(size_t)row * 128 + col] = vl;
    }
  }
}

extern "C" void kernel_launch(void* const* d_in, const int* in_sizes, int n_in,
                              void* d_out, int out_size, void* d_ws, size_t ws_size,
                              hipStream_t stream) {
  const float* a_z  = (const float*)d_in[0];
  const float* bv_z = (const float*)d_in[1];
  const int*   mask = (const int*)d_in[2];
  const float* wgt  = (const float*)d_in[3];
  const float* ipw  = (const float*)d_in[4];
  const float* ipb  = (const float*)d_in[5];
  const float* ow   = (const float*)d_in[6];
  const float* ob   = (const float*)d_in[7];
  float* topic = (float*)d_out;              // [4096 x 128]
  float* infl  = (float*)d_out + 4096 * 128; // [4096]

  const size_t MB = (size_t)1 << 20;
  char* ws = (char*)d_ws;
  short* Qb     = (short*)(ws);                    // 4 MB
  short* Kp     = (short*)(ws + 4 * MB);           // 4 MB packed K frags
  short* Vp     = (short*)(ws + 8 * MB);           // 4 MB packed V frags
  short* ctxb   = (short*)(ws + 12 * MB);          // 4 MB
  float* validw = (float*)(ws + 16 * MB);          // 16 KB
  short* Wf     = (short*)(ws + 16 * MB + (64 << 10));   // 128 KB
  float* bfo    = (float*)(ws + 16 * MB + (224 << 10));  // 512 B
  const size_t pbase0 = 16 * MB + (256 << 10);

  // per split: Opart 4MB + lpart 64KB + cipart 64KB + lbpart 16KB
  auto need = [&](int S) { return pbase0 + (size_t)S * (4 * MB + (144 << 10)); };
  int S = 4;
  while (S > 1 && need(S) > ws_size) S >>= 1;

  char* pbase = ws + pbase0;
  short* Opart  = (short*)(pbase);
  float* lpart  = (float*)(pbase + (size_t)S * 4 * MB);
  float* cipart = (float*)(pbase + (size_t)S * 4 * MB + ((size_t)S << 16));
  float* lbpart = (float*)(pbase + (size_t)S * 4 * MB + ((size_t)S << 17));

  k_qkv <<<768, 256, 0, stream>>>(a_z, bv_z, ipw, ipb, Qb, Kp, Vp);
  k_fold<<<256, 256, 0, stream>>>(ow, ob, Wf, bfo);
  k_attn<<<256 * S, 256, 0, stream>>>(Qb, Kp, Vp, wgt, mask, S, Opart, lpart, cipart, lbpart);
  k_comb<<<512, 256, 0, stream>>>(Opart, lpart, cipart, lbpart, S, ctxb, validw, infl);
  k_out <<<256, 256, 0, stream>>>(ctxb, Wf, bfo, validw, topic);
}